// Round 4
// baseline (1240.477 us; speedup 1.0000x reference)
//
#include <hip/hip_runtime.h>

// Problem constants (MyHead_67242007986918)
#define NPTS 80000      // B*NP
#define NPER 20000      // NP per batch
#define CDIM 256
#define NNB  16
#define NKP  15
#define NCLS 17
#define GSH  32
#define GSW  128

typedef __bf16 bf16x8 __attribute__((ext_vector_type(8)));
typedef float  f32x4  __attribute__((ext_vector_type(4)));
typedef float  f32x2  __attribute__((ext_vector_type(2)));

__device__ __forceinline__ float bf2f_lo(unsigned int u){ return __uint_as_float(u << 16); }
__device__ __forceinline__ float bf2f_hi(unsigned int u){ return __uint_as_float(u & 0xFFFF0000u); }
__device__ __forceinline__ unsigned short f2bf(float f){
    unsigned int u = __float_as_uint(f);
    u = u + 0x7FFFu + ((u >> 16) & 1u);     // RNE
    return (unsigned short)(u >> 16);
}
__device__ __forceinline__ unsigned int pack2(float a, float b){
    return (unsigned int)f2bf(a) | ((unsigned int)f2bf(b) << 16);
}

// ---------------- ws layout (R1-verified footprint) ----------------
// feats  bf16 [NPTS][256]          :      0 .. 40,960,000
// kpwT   bf16 [15][256 d][256 c]   : 40,960,000 .. 42,926,080
// outbuf f32  [NPTS][256]          : 42,926,080 .. 124,846,080
// stats  f32  [512] (sum, sumsq)   : 124,846,080 .. 124,848,128
#define WS_KPWT   40960000
#define WS_OUT    42926080
#define WS_STATS  124846080
#define WS_NEED   124848128

__global__ void zero_stats_kernel(float* stats){ stats[threadIdx.x] = 0.f; }   // <<<1,512>>>

// Fused rearrange + bilinear grid-sample (border pad, align_corners=False) -> bf16 feats
__global__ __launch_bounds__(256) void gs_kernel(
    const float* __restrict__ x, const float* __restrict__ px,
    const float* __restrict__ py, unsigned short* __restrict__ feats)
{
    int gid = blockIdx.x * 256 + threadIdx.x;           // 80000*64 threads
    int n = gid >> 6;
    if (n >= NPTS) return;
    int c0 = (gid & 63) << 2;
    int b = n / NPER;
    float ix = fminf(fmaxf(((px[n] + 1.f) * (float)GSW - 1.f) * 0.5f, 0.f), (float)(GSW - 1));
    float iy = fminf(fmaxf(((py[n] + 1.f) * (float)GSH - 1.f) * 0.5f, 0.f), (float)(GSH - 1));
    float x0f = floorf(ix), y0f = floorf(iy);
    float wx = ix - x0f, wy = iy - y0f;
    int x0 = (int)x0f, y0 = (int)y0f;
    int x1 = min(x0 + 1, GSW - 1), y1 = min(y0 + 1, GSH - 1);
    const float* base = x + (size_t)b * (GSH * GSW * CDIM);
    float4 v00 = *(const float4*)(base + ((size_t)(y0 * GSW + x0)) * CDIM + c0);
    float4 v01 = *(const float4*)(base + ((size_t)(y0 * GSW + x1)) * CDIM + c0);
    float4 v10 = *(const float4*)(base + ((size_t)(y1 * GSW + x0)) * CDIM + c0);
    float4 v11 = *(const float4*)(base + ((size_t)(y1 * GSW + x1)) * CDIM + c0);
    float w00 = (1.f - wx) * (1.f - wy), w01 = wx * (1.f - wy);
    float w10 = (1.f - wx) * wy,         w11 = wx * wy;
    float r0 = v00.x * w00 + v01.x * w01 + v10.x * w10 + v11.x * w11;
    float r1 = v00.y * w00 + v01.y * w01 + v10.y * w10 + v11.y * w11;
    float r2 = v00.z * w00 + v01.z * w01 + v10.z * w10 + v11.z * w11;
    float r3 = v00.w * w00 + v01.w * w01 + v10.w * w10 + v11.w * w11;
    ushort4 o; o.x = f2bf(r0); o.y = f2bf(r1); o.z = f2bf(r2); o.w = f2bf(r3);
    *(ushort4*)(feats + (size_t)n * CDIM + c0) = o;
}

// kp_weights [k][c][d] f32 -> kpwT [15][d][c] bf16.
__global__ __launch_bounds__(256) void wt_kernel(
    const float* __restrict__ kpw, unsigned short* __restrict__ kpwT)
{
    int gid = blockIdx.x * 256 + threadIdx.x;           // 15*65536 = 983,040 -> 3840 blocks
    int k = gid >> 16;
    int c = (gid >> 8) & 255;
    int d = gid & 255;
    kpwT[(k << 16) + (d << 8) + c] = f2bf(kpw[gid]);
}

// Fused KPConv. Block = 256 thr (4 waves), 64-pt tile processed as two 32-pt halves.
// LDS ~64.2KB -> 2 blocks/CU. Chunk = 32 feature channels, staged as 64B segments.
// Register budget: acc[2][4]=32 + wf[8][2]=32 + foff 8 + temps -> no spills.
__global__ __launch_bounds__(256, 2) void kpconv_kernel(
    const unsigned short* __restrict__ feats,
    const unsigned short* __restrict__ kpwT,
    const int*   __restrict__ pknn,
    const float* __restrict__ pxyz,
    const float* __restrict__ kp_pts,
    float* __restrict__ outbuf,
    float* __restrict__ stats)
{
    __shared__ unsigned short s_fN[16][32][32];          // [a][p][c32] 32KB
    __shared__ unsigned short s_w[2][16][32][8];         // [kh][a][p][k8] 16KB
    __shared__ unsigned short s_wf[4 * 2 * 2 * 4 * 16 * 8]; // [pair][chh][rt][qw][m][8] 16KB
    __shared__ float s_kp[NKP * 3];

    int tid = threadIdx.x;
    int n0  = blockIdx.x * 64;

    if (tid < NKP * 3) s_kp[tid] = kp_pts[tid];

    int wv = tid >> 6, lane = tid & 63, m = lane & 15, q = lane >> 4;
    // phase-1 ids: 32 points x 8 threads (4 channels each)
    int p1 = tid >> 3, cg = tid & 7;
    int rt1 = p1 >> 4, m1 = p1 & 15;
    int chh1 = cg >> 2, qbit = (cg >> 1) & 1, off1 = (cg & 1) * 4;
    // stager ids: 4 lanes x 16B per row
    int ps = (tid >> 2) & 31, bs = tid >> 7, part = tid & 3;
    // w-phase ids: 32 points x 8 threads (2 a's each)
    int pw = tid >> 3, jw = tid & 7;

    __syncthreads();                                     // s_kp visible

    for (int half = 0; half < 2; half++){
        int base = n0 + 32 * half;

        // ---- stager foffs: thread handles rows (ps, a=2i+bs), part (tid&3) ----
        int foff[8];
        {
            int n = base + ps;
            int b = n / NPER;
#pragma unroll
            for (int i = 0; i < 8; i++){
                int a = 2 * i + bs;
                int nb = pknn[(size_t)n * NNB + a];
                foff[i] = (b * NPER + nb) * CDIM + part * 8;
            }
        }

        // ---- w-phase: w[a][p][k] = relu(1 - |dxyz - kp_k|/1.2), bf16 ----
        {
            int n = base + pw;
            int b = n / NPER;
            float cx = pxyz[n * 3 + 0], cy = pxyz[n * 3 + 1], cz = pxyz[n * 3 + 2];
#pragma unroll
            for (int i = 0; i < 2; i++){
                int a = jw + 8 * i;
                int g = b * NPER + pknn[(size_t)n * NNB + a];
                float dx = pxyz[g * 3 + 0] - cx;
                float dy = pxyz[g * 3 + 1] - cy;
                float dz = pxyz[g * 3 + 2] - cz;
#pragma unroll
                for (int k = 0; k < NKP; k++){
                    float ex = dx - s_kp[k * 3 + 0], ey = dy - s_kp[k * 3 + 1], ez = dz - s_kp[k * 3 + 2];
                    float w = fmaxf(1.f - sqrtf(ex * ex + ey * ey + ez * ez) * (1.f / 1.2f), 0.f);
                    s_w[k >> 3][a][pw][k & 7] = f2bf(w);
                }
                s_w[1][a][pw][7] = 0;
            }
        }

        f32x4 acc[2][4];
#pragma unroll
        for (int i = 0; i < 2; i++)
#pragma unroll
            for (int j = 0; j < 4; j++){ acc[i][j][0]=0.f; acc[i][j][1]=0.f; acc[i][j][2]=0.f; acc[i][j][3]=0.f; }

        __syncthreads();                                 // s_w ready; prev-half done with LDS

        for (int ch = 0; ch < 8; ch++){                  // 32-channel chunks
            int cb = ch * 32;
            // ---- stage: 512 rows x 64B, 64B contiguous segments (4 lanes x 16B) ----
#pragma unroll
            for (int i = 0; i < 8; i++){
                uint4 v = *(const uint4*)(feats + (size_t)(foff[i] + cb));
                *(uint4*)&s_fN[2 * i + bs][ps][part * 8] = v;
            }
            __syncthreads();

#pragma unroll
            for (int kh = 0; kh < 2; kh++){
                // ---- phase 1: wf[8 k][4 ch] over a=0..15 ----
                f32x2 wf[8][2];
#pragma unroll
                for (int kk = 0; kk < 8; kk++){ wf[kk][0] = (f32x2)0.f; wf[kk][1] = (f32x2)0.f; }
#pragma unroll
                for (int a = 0; a < 16; a++){
                    uint2 fv = *(const uint2*)&s_fN[a][p1][cg * 4];
                    f32x2 fa0; fa0[0] = bf2f_lo(fv.x); fa0[1] = bf2f_hi(fv.x);
                    f32x2 fa1; fa1[0] = bf2f_lo(fv.y); fa1[1] = bf2f_hi(fv.y);
                    uint4 wr = *(const uint4*)&s_w[kh][a][p1][0];
                    float wk[8];
                    wk[0]=bf2f_lo(wr.x); wk[1]=bf2f_hi(wr.x); wk[2]=bf2f_lo(wr.y); wk[3]=bf2f_hi(wr.y);
                    wk[4]=bf2f_lo(wr.z); wk[5]=bf2f_hi(wr.z); wk[6]=bf2f_lo(wr.w); wk[7]=bf2f_hi(wr.w);
#pragma unroll
                    for (int kk = 0; kk < 8; kk++){
                        f32x2 w2; w2[0] = wk[kk]; w2[1] = wk[kk];
                        wf[kk][0] = w2 * fa0 + wf[kk][0];
                        wf[kk][1] = w2 * fa1 + wf[kk][1];
                    }
                }
                __syncthreads();                         // prev MFMA done reading s_wf
                // ---- pack -> s_wf[pair][chh][rt][qw][m][8]; phantom k=15 -> zeros ----
#pragma unroll
                for (int kk = 0; kk < 8; kk++){
                    uint2 o;
                    if (kh == 1 && kk == 7){ o.x = 0u; o.y = 0u; }
                    else {
                        o.x = pack2(wf[kk][0][0], wf[kk][0][1]);
                        o.y = pack2(wf[kk][1][0], wf[kk][1][1]);
                    }
                    int pair = kk >> 1, qw = (kk & 1) * 2 + qbit;
                    int flat = ((((pair * 2 + chh1) * 2 + rt1) * 4 + qw) * 16 + m1) * 8 + off1;
                    *(uint2*)&s_wf[flat] = o;
                }
                __syncthreads();
                // ---- phase 2: MFMA 16x16x32; Kwin = 2k x 16ch ----
#pragma unroll
                for (int pair = 0; pair < 4; pair++){
                    int k = kh * 8 + 2 * pair + (q >> 1);
                    int keff = (k < NKP) ? k : 0;        // phantom: A==0
#pragma unroll
                    for (int chh = 0; chh < 2; chh++){
                        bf16x8 A[2];
#pragma unroll
                        for (int rt = 0; rt < 2; rt++)
                            A[rt] = *(const bf16x8*)&s_wf[((((pair * 2 + chh) * 2 + rt) * 4 + q) * 16 + m) * 8];
                        const unsigned short* bb = kpwT + ((size_t)keff << 16) + cb + chh * 16 + (q & 1) * 8;
#pragma unroll
                        for (int ct = 0; ct < 4; ct++){
                            int d = wv * 64 + ct * 16 + m;
                            bf16x8 Bf = *(const bf16x8*)(bb + d * 256);
#pragma unroll
                            for (int rt = 0; rt < 2; rt++)
                                acc[rt][ct] = __builtin_amdgcn_mfma_f32_16x16x32_bf16(A[rt], Bf, acc[rt][ct], 0, 0, 0);
                        }
                    }
                }
                __syncthreads();
            }
        }

        // ---- epilogue (per half): store fp32 + BN partial sums ----
#pragma unroll
        for (int rt = 0; rt < 2; rt++)
#pragma unroll
            for (int ct = 0; ct < 4; ct++)
#pragma unroll
                for (int r = 0; r < 4; r++){
                    int prow = 16 * rt + 4 * q + r;      // C/D: row=(lane>>4)*4+r, col=lane&15
                    int d = wv * 64 + ct * 16 + m;
                    outbuf[(size_t)(base + prow) * CDIM + d] = acc[rt][ct][r];
                }
#pragma unroll
        for (int ct = 0; ct < 4; ct++){
            float s1 = 0.f, s2 = 0.f;
#pragma unroll
            for (int rt = 0; rt < 2; rt++)
#pragma unroll
                for (int r = 0; r < 4; r++){
                    float v = acc[rt][ct][r];
                    s1 += v; s2 += v * v;
                }
            s1 += __shfl_xor(s1, 16); s1 += __shfl_xor(s1, 32);
            s2 += __shfl_xor(s2, 16); s2 += __shfl_xor(s2, 32);
            if (q == 0){
                int d = wv * 64 + ct * 16 + m;
                atomicAdd(&stats[d], s1);
                atomicAdd(&stats[256 + d], s2);
            }
        }
        // next half's w-phase writes s_w after the kh-loop's trailing barrier
    }
}

// BN (batch stats) + ReLU + 1x1 conv head. 16 points per block.
__global__ __launch_bounds__(256) void head_kernel(
    const float* __restrict__ outbuf, const float* __restrict__ stats,
    const float* __restrict__ gamma,  const float* __restrict__ beta,
    const float* __restrict__ hw,     const float* __restrict__ hb,
    float* __restrict__ logits)
{
    __shared__ float s_h[16][256];
    int tid = threadIdx.x;
    int n0 = blockIdx.x * 16;
    int pt = tid >> 4, cgr = tid & 15;
    {
        int n = n0 + pt;
        const float invN = 1.f / (float)NPTS;
#pragma unroll
        for (int j = 0; j < 16; j += 4){
            int c = cgr * 16 + j;
            float4 v  = *(const float4*)(outbuf + (size_t)n * CDIM + c);
            float4 su = *(const float4*)(stats + c);
            float4 sq = *(const float4*)(stats + 256 + c);
            float4 ga = *(const float4*)(gamma + c);
            float4 be = *(const float4*)(beta + c);
            float mean, var;
            mean = su.x * invN; var = sq.x * invN - mean * mean;
            s_h[pt][c + 0] = fmaxf(ga.x * (v.x - mean) * rsqrtf(var + 1e-5f) + be.x, 0.f);
            mean = su.y * invN; var = sq.y * invN - mean * mean;
            s_h[pt][c + 1] = fmaxf(ga.y * (v.y - mean) * rsqrtf(var + 1e-5f) + be.y, 0.f);
            mean = su.z * invN; var = sq.z * invN - mean * mean;
            s_h[pt][c + 2] = fmaxf(ga.z * (v.z - mean) * rsqrtf(var + 1e-5f) + be.z, 0.f);
            mean = su.w * invN; var = sq.w * invN - mean * mean;
            s_h[pt][c + 3] = fmaxf(ga.w * (v.w - mean) * rsqrtf(var + 1e-5f) + be.w, 0.f);
        }
    }
    __syncthreads();
    for (int idx = tid; idx < 16 * NCLS; idx += 256){
        int pt2 = idx / NCLS, cls = idx - pt2 * NCLS;
        float acc = hb[cls];
#pragma unroll 8
        for (int c = 0; c < CDIM; c += 4){
            float4 h4 = *(const float4*)&s_h[pt2][c];
            float4 w4 = *(const float4*)(hw + (size_t)cls * CDIM + c);
            acc = fmaf(h4.x, w4.x, fmaf(h4.y, w4.y, fmaf(h4.z, w4.z, fmaf(h4.w, w4.w, acc))));
        }
        logits[(size_t)(n0 + pt2) * NCLS + cls] = acc;
    }
}

extern "C" void kernel_launch(void* const* d_in, const int* in_sizes, int n_in,
                              void* d_out, int out_size, void* d_ws, size_t ws_size,
                              hipStream_t stream)
{
    (void)in_sizes; (void)n_in; (void)out_size;
    if (ws_size < (size_t)WS_NEED) return;   // R1-verified footprint (119.06 MB)

    const float* x      = (const float*)d_in[0];
    // d_in[1] = skip  : dead code in reference
    const float* px     = (const float*)d_in[2];
    const float* py     = (const float*)d_in[3];
    const float* pxyz   = (const float*)d_in[4];
    const int*   pknn   = (const int*)  d_in[5];
    // d_in[6] = num_points : unused
    const float* kp_pts = (const float*)d_in[7];
    const float* kpw    = (const float*)d_in[8];
    const float* gamma  = (const float*)d_in[9];
    const float* beta   = (const float*)d_in[10];
    const float* hw     = (const float*)d_in[11];
    const float* hb     = (const float*)d_in[12];
    float* logits = (float*)d_out;

    char* ws = (char*)d_ws;
    unsigned short* feats = (unsigned short*)(ws);
    unsigned short* kpwT  = (unsigned short*)(ws + WS_KPWT);
    float* outbuf = (float*)(ws + WS_OUT);
    float* stats  = (float*)(ws + WS_STATS);

    hipLaunchKernelGGL(zero_stats_kernel, dim3(1),     dim3(512), 0, stream, stats);
    hipLaunchKernelGGL(gs_kernel,         dim3(20000), dim3(256), 0, stream, x, px, py, feats);
    hipLaunchKernelGGL(wt_kernel,         dim3(3840),  dim3(256), 0, stream, kpw, kpwT);
    hipLaunchKernelGGL(kpconv_kernel,     dim3(1250),  dim3(256), 0, stream,
                       feats, kpwT, pknn, pxyz, kp_pts, outbuf, stats);
    hipLaunchKernelGGL(head_kernel,       dim3(5000),  dim3(256), 0, stream,
                       outbuf, stats, gamma, beta, hw, hb, logits);
}

// Round 5
// 845.736 us; speedup vs baseline: 1.4667x; 1.4667x over previous
//
#include <hip/hip_runtime.h>

// Problem constants (MyHead_67242007986918)
#define NPTS 80000      // B*NP
#define NPER 20000      // NP per batch
#define CDIM 256
#define NNB  16
#define NKP  15
#define NCLS 17
#define GSH  32
#define GSW  128

typedef __bf16 bf16x8 __attribute__((ext_vector_type(8)));
typedef float  f32x4  __attribute__((ext_vector_type(4)));
typedef float  f32x2  __attribute__((ext_vector_type(2)));

__device__ __forceinline__ float bf2f_lo(unsigned int u){ return __uint_as_float(u << 16); }
__device__ __forceinline__ float bf2f_hi(unsigned int u){ return __uint_as_float(u & 0xFFFF0000u); }
__device__ __forceinline__ unsigned short f2bf(float f){
    unsigned int u = __float_as_uint(f);
    u = u + 0x7FFFu + ((u >> 16) & 1u);     // RNE
    return (unsigned short)(u >> 16);
}
__device__ __forceinline__ unsigned int pack2(float a, float b){
    return (unsigned int)f2bf(a) | ((unsigned int)f2bf(b) << 16);
}

// async global->LDS, 16B per lane; lds dest = wave-uniform base + lane*16
#define GLD_LDS16(gsrc, ldst) \
    __builtin_amdgcn_global_load_lds((const __attribute__((address_space(1))) unsigned int*)(gsrc), \
                                     (__attribute__((address_space(3))) unsigned int*)(ldst), 16, 0, 0)

// ---------------- ws layout (R1-verified footprint, 124,848,128 B) ----------------
// feats  bf16 [NPTS][256]            :      0 .. 40,960,000
// kpwS   bf16 swizzled B (983040 el) : 40,960,000 .. 42,926,080
// outbuf f32  [NPTS][256]            : 42,926,080 .. 124,846,080
// stats  f32  [512] (sum, sumsq)     : 124,846,080 .. 124,848,128
#define WS_KPWT   40960000
#define WS_OUT    42926080
#define WS_STATS  124846080
#define WS_NEED   124848128

// swizzled B geometry: window (chunk c, pair P) holds K=32 = {k=2P+kwin} x {16 ch}
//  P<7 : block 8192 elems at (c*7+P)*8192 ; elem = (ctg*64 + q*16+m)*8 + j
//  P==7: block 4096 elems at 917504 + c*4096 (kwin0=k14 only); elem = (ctg*32 + (q&1)*16+m)*8 + j
#define B7_BASE 917504

__global__ void zero_stats_kernel(float* stats){ stats[threadIdx.x] = 0.f; }   // <<<1,512>>>

// Fused rearrange + bilinear grid-sample (border pad, align_corners=False) -> bf16 feats
__global__ __launch_bounds__(256) void gs_kernel(
    const float* __restrict__ x, const float* __restrict__ px,
    const float* __restrict__ py, unsigned short* __restrict__ feats)
{
    int gid = blockIdx.x * 256 + threadIdx.x;           // 80000*64 threads
    int n = gid >> 6;
    if (n >= NPTS) return;
    int c0 = (gid & 63) << 2;
    int b = n / NPER;
    float ix = fminf(fmaxf(((px[n] + 1.f) * (float)GSW - 1.f) * 0.5f, 0.f), (float)(GSW - 1));
    float iy = fminf(fmaxf(((py[n] + 1.f) * (float)GSH - 1.f) * 0.5f, 0.f), (float)(GSH - 1));
    float x0f = floorf(ix), y0f = floorf(iy);
    float wx = ix - x0f, wy = iy - y0f;
    int x0 = (int)x0f, y0 = (int)y0f;
    int x1 = min(x0 + 1, GSW - 1), y1 = min(y0 + 1, GSH - 1);
    const float* base = x + (size_t)b * (GSH * GSW * CDIM);
    float4 v00 = *(const float4*)(base + ((size_t)(y0 * GSW + x0)) * CDIM + c0);
    float4 v01 = *(const float4*)(base + ((size_t)(y0 * GSW + x1)) * CDIM + c0);
    float4 v10 = *(const float4*)(base + ((size_t)(y1 * GSW + x0)) * CDIM + c0);
    float4 v11 = *(const float4*)(base + ((size_t)(y1 * GSW + x1)) * CDIM + c0);
    float w00 = (1.f - wx) * (1.f - wy), w01 = wx * (1.f - wy);
    float w10 = (1.f - wx) * wy,         w11 = wx * wy;
    float r0 = v00.x * w00 + v01.x * w01 + v10.x * w10 + v11.x * w11;
    float r1 = v00.y * w00 + v01.y * w01 + v10.y * w10 + v11.y * w11;
    float r2 = v00.z * w00 + v01.z * w01 + v10.z * w10 + v11.z * w11;
    float r3 = v00.w * w00 + v01.w * w01 + v10.w * w10 + v11.w * w11;
    ushort4 o; o.x = f2bf(r0); o.y = f2bf(r1); o.z = f2bf(r2); o.w = f2bf(r3);
    *(ushort4*)(feats + (size_t)n * CDIM + c0) = o;
}

// kp_weights [k][c][d] f32 -> swizzled MFMA-B-fragment order (see geometry above).
// Reads coalesced; writes scatter into the L2-resident 2MB buffer.
__global__ __launch_bounds__(256) void wt_kernel(
    const float* __restrict__ kpw, unsigned short* __restrict__ kpwS)
{
    int gid = blockIdx.x * 256 + threadIdx.x;           // 15*65536 = 983,040 -> 3840 blocks
    int k = gid >> 16;
    int c = (gid >> 8) & 255;
    int d = gid & 255;
    unsigned short v = f2bf(kpw[gid]);
    int pair = k >> 1, kwin = k & 1, chunk = c >> 4, cl = c & 15;
    int kap = kwin * 16 + cl;                           // K-elem within window
    int q = kap >> 3, j = kap & 7;
    int m = d & 15, ctg = d >> 4;
    int idx;
    if (pair < 7) idx = (chunk * 7 + pair) * 8192 + (ctg * 64 + q * 16 + m) * 8 + j;
    else          idx = B7_BASE + chunk * 4096 + (ctg * 32 + q * 16 + m) * 8 + j;  // k=14 -> kwin0, q in {0,1}
    kpwS[idx] = v;
}

// Fused KPConv. Block = 256 thr (4 waves), 64-pt tile, 256 output channels.
// LDS 64KB -> 2 blocks/CU. 16-ch chunks, 2 barriers per chunk.
__global__ __launch_bounds__(256, 2) void kpconv_kernel(
    const unsigned short* __restrict__ feats,
    const unsigned short* __restrict__ kpwS,
    const int*   __restrict__ pknn,
    const float* __restrict__ pxyz,
    const float* __restrict__ kp_pts,
    float* __restrict__ outbuf,
    float* __restrict__ stats)
{
    __shared__ unsigned short s_fN[16384];   // 32KB [wv4][a16][pl16][cl16] (wave-private slabs)
    __shared__ unsigned short s_wf[16384];   // 32KB [k16][p64][cl16]; rows 8..15 double as per-kh w-window

    int tid = threadIdx.x;
    int n0  = blockIdx.x * 64;
    int wv = tid >> 6, lane = tid & 63, m = lane & 15, q = lane >> 4;
    int p1 = tid >> 2, cg = tid & 3, pl1 = p1 & 15;

    // ---- stager row bases (chunk 0), 8 x (a,pl,half) per lane ----
    int fb[8];
    {
        int pl = (lane >> 1) & 15, half = lane & 1;
        int n = n0 + wv * 16 + pl;
        int b = n / NPER;
#pragma unroll
        for (int i = 0; i < 8; i++){
            int a = 2 * i + (lane >> 5);
            fb[i] = (b * NPER + pknn[(size_t)n * NNB + a]) * CDIM + half * 8;
        }
    }

    // ---- w-phase: wreg[i][j] = bf16 pair (k=2j, 2j+1) for a = 4*cg+i ----
    unsigned int wreg[4][8];
    {
        int n = n0 + p1;
        int b = n / NPER;
        float cx = pxyz[n * 3 + 0], cy = pxyz[n * 3 + 1], cz = pxyz[n * 3 + 2];
#pragma unroll
        for (int i = 0; i < 4; i++){
            int a = 4 * cg + i;
            int g = b * NPER + pknn[(size_t)n * NNB + a];
            float dx = pxyz[g * 3 + 0] - cx;
            float dy = pxyz[g * 3 + 1] - cy;
            float dz = pxyz[g * 3 + 2] - cz;
            float w[NKP];
#pragma unroll
            for (int k = 0; k < NKP; k++){
                float ex = dx - kp_pts[k * 3 + 0], ey = dy - kp_pts[k * 3 + 1], ez = dz - kp_pts[k * 3 + 2];
                w[k] = fmaxf(1.f - sqrtf(ex * ex + ey * ey + ez * ez) * (1.f / 1.2f), 0.f);
            }
#pragma unroll
            for (int j = 0; j < 7; j++) wreg[i][j] = pack2(w[2 * j], w[2 * j + 1]);
            wreg[i][7] = pack2(w[14], 0.f);             // k=15 phantom -> 0
        }
    }

    f32x4 acc[4][4];
#pragma unroll
    for (int i = 0; i < 4; i++)
#pragma unroll
        for (int j = 0; j < 4; j++){ acc[i][j][0]=0.f; acc[i][j][1]=0.f; acc[i][j][2]=0.f; acc[i][j][3]=0.f; }

    // ---- initial stage (chunk 0): wave-private slab, async DMA ----
#pragma unroll
    for (int i = 0; i < 8; i++)
        GLD_LDS16(feats + (size_t)fb[i], (char*)s_fN + wv * 8192 + i * 1024);

    for (int c = 0; c < 16; c++){
        asm volatile("s_waitcnt vmcnt(0)" ::: "memory");   // stage(c) landed (wave-local)

#pragma unroll
        for (int kh = 0; kh < 2; kh++){
            // w-window (aliases s_wf rows 8..15, wave-private p1 rows; lockstep-safe)
#pragma unroll
            for (int i = 0; i < 4; i++){
                int a = 4 * cg + i;
                uint4 wv4 = make_uint4(wreg[i][4*kh+0], wreg[i][4*kh+1], wreg[i][4*kh+2], wreg[i][4*kh+3]);
                *(uint4*)&s_wf[((8 + (a >> 1)) * 64 + p1) * 16 + (a & 1) * 8] = wv4;
            }
            // phase 1: wf[8k][4ch] over a = 0..15
            f32x2 wf[8][2];
#pragma unroll
            for (int kk = 0; kk < 8; kk++){ wf[kk][0] = (f32x2)0.f; wf[kk][1] = (f32x2)0.f; }
#pragma unroll
            for (int a = 0; a < 16; a++){
                uint2 fv = *(const uint2*)&s_fN[wv * 4096 + a * 256 + pl1 * 16 + cg * 4];
                uint4 ww = *(const uint4*)&s_wf[((8 + (a >> 1)) * 64 + p1) * 16 + (a & 1) * 8];
                f32x2 fa0; fa0[0] = bf2f_lo(fv.x); fa0[1] = bf2f_hi(fv.x);
                f32x2 fa1; fa1[0] = bf2f_lo(fv.y); fa1[1] = bf2f_hi(fv.y);
                float wk[8];
                wk[0]=bf2f_lo(ww.x); wk[1]=bf2f_hi(ww.x); wk[2]=bf2f_lo(ww.y); wk[3]=bf2f_hi(ww.y);
                wk[4]=bf2f_lo(ww.z); wk[5]=bf2f_hi(ww.z); wk[6]=bf2f_lo(ww.w); wk[7]=bf2f_hi(ww.w);
#pragma unroll
                for (int kk = 0; kk < 8; kk++){
                    f32x2 w2; w2[0] = wk[kk]; w2[1] = wk[kk];
                    wf[kk][0] = w2 * fa0 + wf[kk][0];
                    wf[kk][1] = w2 * fa1 + wf[kk][1];
                }
            }
            // pack -> s_wf[k][p][cl] (kh1 kk7 writes zeros: w15 == 0)
#pragma unroll
            for (int kk = 0; kk < 8; kk++){
                uint2 o;
                o.x = pack2(wf[kk][0][0], wf[kk][0][1]);
                o.y = pack2(wf[kk][1][0], wf[kk][1][1]);
                *(uint2*)&s_wf[((kh * 8 + kk) * 64 + p1) * 16 + cg * 4] = o;
            }
        }

        // issue next chunk's stage now -> overlaps with MFMA phase
        {
            int cn = (c < 15) ? c + 1 : c;               // last iter: harmless re-read
#pragma unroll
            for (int i = 0; i < 8; i++)
                GLD_LDS16(feats + (size_t)(fb[i] + cn * 16), (char*)s_fN + wv * 8192 + i * 1024);
        }

        asm volatile("s_waitcnt lgkmcnt(0)\ns_barrier" ::: "memory");   // wf ready (no vmcnt drain)

        // phase 2: MFMA 16x16x32; window (c,P): K = {2P+kwin} x 16ch
#pragma unroll
        for (int P = 0; P < 8; P++){
            bf16x8 A[4];
#pragma unroll
            for (int rt = 0; rt < 4; rt++)
                A[rt] = *(const bf16x8*)&s_wf[((2 * P + (q >> 1)) * 64 + 16 * rt + m) * 16 + (q & 1) * 8];
            const unsigned short* bb;
            int stride;
            if (P < 7){ bb = kpwS + (c * 7 + P) * 8192 + (q * 16 + m) * 8;              stride = 512; }
            else      { bb = kpwS + B7_BASE + c * 4096 + ((q & 1) * 16 + m) * 8;        stride = 256; }
#pragma unroll
            for (int ct = 0; ct < 4; ct++){
                bf16x8 Bf = *(const bf16x8*)(bb + (wv * 4 + ct) * stride);   // lane-contiguous 1KB burst
#pragma unroll
                for (int rt = 0; rt < 4; rt++)
                    acc[rt][ct] = __builtin_amdgcn_mfma_f32_16x16x32_bf16(A[rt], Bf, acc[rt][ct], 0, 0, 0);
            }
        }

        asm volatile("s_waitcnt lgkmcnt(0)\ns_barrier" ::: "memory");   // wf consumed
    }

    // ---- epilogue: store fp32, fold BN partial sums via atomics ----
#pragma unroll
    for (int rt = 0; rt < 4; rt++)
#pragma unroll
        for (int ct = 0; ct < 4; ct++)
#pragma unroll
            for (int r = 0; r < 4; r++){
                int prow = 16 * rt + 4 * q + r;          // C/D: row=(lane>>4)*4+r, col=lane&15
                int d = wv * 64 + ct * 16 + m;
                outbuf[(size_t)(n0 + prow) * CDIM + d] = acc[rt][ct][r];
            }
#pragma unroll
    for (int ct = 0; ct < 4; ct++){
        float s1 = 0.f, s2 = 0.f;
#pragma unroll
        for (int rt = 0; rt < 4; rt++)
#pragma unroll
            for (int r = 0; r < 4; r++){
                float v = acc[rt][ct][r];
                s1 += v; s2 += v * v;
            }
        s1 += __shfl_xor(s1, 16); s1 += __shfl_xor(s1, 32);
        s2 += __shfl_xor(s2, 16); s2 += __shfl_xor(s2, 32);
        if (q == 0){
            int d = wv * 64 + ct * 16 + m;
            atomicAdd(&stats[d], s1);
            atomicAdd(&stats[256 + d], s2);
        }
    }
}

// BN (batch stats) + ReLU + 1x1 conv head. 16 points per block.
__global__ __launch_bounds__(256) void head_kernel(
    const float* __restrict__ outbuf, const float* __restrict__ stats,
    const float* __restrict__ gamma,  const float* __restrict__ beta,
    const float* __restrict__ hw,     const float* __restrict__ hb,
    float* __restrict__ logits)
{
    __shared__ float s_h[16][256];
    int tid = threadIdx.x;
    int n0 = blockIdx.x * 16;
    int pt = tid >> 4, cgr = tid & 15;
    {
        int n = n0 + pt;
        const float invN = 1.f / (float)NPTS;
#pragma unroll
        for (int j = 0; j < 16; j += 4){
            int c = cgr * 16 + j;
            float4 v  = *(const float4*)(outbuf + (size_t)n * CDIM + c);
            float4 su = *(const float4*)(stats + c);
            float4 sq = *(const float4*)(stats + 256 + c);
            float4 ga = *(const float4*)(gamma + c);
            float4 be = *(const float4*)(beta + c);
            float mean, var;
            mean = su.x * invN; var = sq.x * invN - mean * mean;
            s_h[pt][c + 0] = fmaxf(ga.x * (v.x - mean) * rsqrtf(var + 1e-5f) + be.x, 0.f);
            mean = su.y * invN; var = sq.y * invN - mean * mean;
            s_h[pt][c + 1] = fmaxf(ga.y * (v.y - mean) * rsqrtf(var + 1e-5f) + be.y, 0.f);
            mean = su.z * invN; var = sq.z * invN - mean * mean;
            s_h[pt][c + 2] = fmaxf(ga.z * (v.z - mean) * rsqrtf(var + 1e-5f) + be.z, 0.f);
            mean = su.w * invN; var = sq.w * invN - mean * mean;
            s_h[pt][c + 3] = fmaxf(ga.w * (v.w - mean) * rsqrtf(var + 1e-5f) + be.w, 0.f);
        }
    }
    __syncthreads();
    for (int idx = tid; idx < 16 * NCLS; idx += 256){
        int pt2 = idx / NCLS, cls = idx - pt2 * NCLS;
        float acc = hb[cls];
#pragma unroll 8
        for (int c = 0; c < CDIM; c += 4){
            float4 h4 = *(const float4*)&s_h[pt2][c];
            float4 w4 = *(const float4*)(hw + (size_t)cls * CDIM + c);
            acc = fmaf(h4.x, w4.x, fmaf(h4.y, w4.y, fmaf(h4.z, w4.z, fmaf(h4.w, w4.w, acc))));
        }
        logits[(size_t)(n0 + pt2) * NCLS + cls] = acc;
    }
}

extern "C" void kernel_launch(void* const* d_in, const int* in_sizes, int n_in,
                              void* d_out, int out_size, void* d_ws, size_t ws_size,
                              hipStream_t stream)
{
    (void)in_sizes; (void)n_in; (void)out_size;
    if (ws_size < (size_t)WS_NEED) return;   // R1-verified footprint (119.06 MB)

    const float* x      = (const float*)d_in[0];
    // d_in[1] = skip  : dead code in reference
    const float* px     = (const float*)d_in[2];
    const float* py     = (const float*)d_in[3];
    const float* pxyz   = (const float*)d_in[4];
    const int*   pknn   = (const int*)  d_in[5];
    // d_in[6] = num_points : unused
    const float* kp_pts = (const float*)d_in[7];
    const float* kpw    = (const float*)d_in[8];
    const float* gamma  = (const float*)d_in[9];
    const float* beta   = (const float*)d_in[10];
    const float* hw     = (const float*)d_in[11];
    const float* hb     = (const float*)d_in[12];
    float* logits = (float*)d_out;

    char* ws = (char*)d_ws;
    unsigned short* feats = (unsigned short*)(ws);
    unsigned short* kpwS  = (unsigned short*)(ws + WS_KPWT);
    float* outbuf = (float*)(ws + WS_OUT);
    float* stats  = (float*)(ws + WS_STATS);

    hipLaunchKernelGGL(zero_stats_kernel, dim3(1),     dim3(512), 0, stream, stats);
    hipLaunchKernelGGL(gs_kernel,         dim3(20000), dim3(256), 0, stream, x, px, py, feats);
    hipLaunchKernelGGL(wt_kernel,         dim3(3840),  dim3(256), 0, stream, kpw, kpwS);
    hipLaunchKernelGGL(kpconv_kernel,     dim3(1250),  dim3(256), 0, stream,
                       feats, kpwS, pknn, pxyz, kp_pts, outbuf, stats);
    hipLaunchKernelGGL(head_kernel,       dim3(5000),  dim3(256), 0, stream,
                       outbuf, stats, gamma, beta, hw, hb, logits);
}